// Round 1
// baseline (1449.514 us; speedup 1.0000x reference)
//
#include <hip/hip_runtime.h>
#include <hip/hip_bf16.h>
#include <math.h>

#define B_ 4
#define S_ 1024
#define E_ 1024
#define H_ 16
#define D_ 64
#define BH_ 64
#define M_ 4096
#define BHSD ((size_t)4194304)  // B*H*S*D

// ---------------------------------------------------------------------------
// K1: qkv[m][n] = sum_k X[m][k] * Wqkv[n][k]   (M=4096, N=3072, K=1024)
// Epilogue: RoPE on q,k (which<2), scatter to ws as (3,B,H,S,D) fp32.
// ---------------------------------------------------------------------------
__global__ __launch_bounds__(256) void k_qkv_rope(
    const float* __restrict__ X, const float* __restrict__ W,
    const float* __restrict__ cosb, const float* __restrict__ sinb,
    float* __restrict__ qkv) {
  __shared__ float As[16][68];  // [k][m], padded
  __shared__ float Bs[16][68];  // [k][n], padded
  const int t = threadIdx.x;
  const int tx = t & 15, ty = t >> 4;
  const int m0 = blockIdx.y * 64, n0 = blockIdx.x * 64;
  const int lr = t >> 2;        // 0..63 tile row
  const int lc = (t & 3) * 4;   // 0,4,8,12 k-col
  float acc[4][4] = {};
  for (int k0 = 0; k0 < 1024; k0 += 16) {
    float4 av = *(const float4*)&X[(size_t)(m0 + lr) * 1024 + k0 + lc];
    float4 bv = *(const float4*)&W[(size_t)(n0 + lr) * 1024 + k0 + lc];
    __syncthreads();
    As[lc + 0][lr] = av.x; As[lc + 1][lr] = av.y; As[lc + 2][lr] = av.z; As[lc + 3][lr] = av.w;
    Bs[lc + 0][lr] = bv.x; Bs[lc + 1][lr] = bv.y; Bs[lc + 2][lr] = bv.z; Bs[lc + 3][lr] = bv.w;
    __syncthreads();
#pragma unroll
    for (int kk = 0; kk < 16; ++kk) {
      float4 a = *(const float4*)&As[kk][ty * 4];
      float4 b = *(const float4*)&Bs[kk][tx * 4];
      acc[0][0] += a.x * b.x; acc[0][1] += a.x * b.y; acc[0][2] += a.x * b.z; acc[0][3] += a.x * b.w;
      acc[1][0] += a.y * b.x; acc[1][1] += a.y * b.y; acc[1][2] += a.y * b.z; acc[1][3] += a.y * b.w;
      acc[2][0] += a.z * b.x; acc[2][1] += a.z * b.y; acc[2][2] += a.z * b.z; acc[2][3] += a.z * b.w;
      acc[3][0] += a.w * b.x; acc[3][1] += a.w * b.y; acc[3][2] += a.w * b.z; acc[3][3] += a.w * b.w;
    }
  }
  // epilogue: RoPE + scatter
  const int nb = n0 + tx * 4;       // 4-aligned, within one (which,h) 64-block
  const int which = nb >> 10;       // 0=q 1=k 2=v
  const int e = nb & 1023;
  const int h = e >> 6;
  const int d0 = e & 63;            // 4-aligned
#pragma unroll
  for (int i = 0; i < 4; ++i) {
    const int m = m0 + ty * 4 + i;
    const int b = m >> 10, s = m & 1023;
    const float v0 = acc[i][0], v1 = acc[i][1], v2 = acc[i][2], v3 = acc[i][3];
    float4 o;
    if (which < 2) {
      const float c0 = cosb[s * 64 + d0],     s0 = sinb[s * 64 + d0];
      const float c1 = cosb[s * 64 + d0 + 2], s1 = sinb[s * 64 + d0 + 2];
      o.x = v0 * c0 - v1 * s0;
      o.y = v0 * s0 + v1 * c0;
      o.z = v2 * c1 - v3 * s1;
      o.w = v2 * s1 + v3 * c1;
    } else {
      o = make_float4(v0, v1, v2, v3);
    }
    const size_t off = (size_t)which * BHSD +
                       (((size_t)(b * H_ + h) * S_ + s) * D_) + d0;
    *(float4*)&qkv[off] = o;
  }
}

// ---------------------------------------------------------------------------
// K2: raw scores = Q Kt / 8 + mask  → attn region (pre-softmax)
// block: 32 q-rows of one (b,h); loops k-tiles of 64
// ---------------------------------------------------------------------------
__global__ __launch_bounds__(256) void k_scores(
    const float* __restrict__ qws, const float* __restrict__ kws,
    const float* __restrict__ mask, float* __restrict__ attn) {
  __shared__ float Qs[32][68];
  __shared__ float Ks[64][68];
  const int t = threadIdx.x;
  const int bh = blockIdx.y;
  const int q0 = blockIdx.x * 32;
  const size_t qbase = ((size_t)bh * S_ + q0) * D_;
  {
    const int r = t >> 3, c = (t & 7) * 8;
    float4 a = *(const float4*)&qws[qbase + r * 64 + c];
    float4 b = *(const float4*)&qws[qbase + r * 64 + c + 4];
    *(float4*)&Qs[r][c] = a;
    *(float4*)&Qs[r][c + 4] = b;
  }
  const int tx = t & 15, ty = t >> 4;
  for (int k0 = 0; k0 < S_; k0 += 64) {
    __syncthreads();
    for (int idx = t; idx < 64 * 16; idx += 256) {
      const int r = idx >> 4, c = (idx & 15) * 4;
      float4 kv = *(const float4*)&kws[((size_t)bh * S_ + k0 + r) * D_ + c];
      *(float4*)&Ks[r][c] = kv;
    }
    __syncthreads();
    float acc[2][4] = {};
#pragma unroll
    for (int d4 = 0; d4 < 16; ++d4) {
      float4 q0v = *(const float4*)&Qs[ty * 2 + 0][d4 * 4];
      float4 q1v = *(const float4*)&Qs[ty * 2 + 1][d4 * 4];
      float4 ka = *(const float4*)&Ks[tx * 4 + 0][d4 * 4];
      float4 kb = *(const float4*)&Ks[tx * 4 + 1][d4 * 4];
      float4 kc = *(const float4*)&Ks[tx * 4 + 2][d4 * 4];
      float4 kd = *(const float4*)&Ks[tx * 4 + 3][d4 * 4];
      acc[0][0] += q0v.x * ka.x + q0v.y * ka.y + q0v.z * ka.z + q0v.w * ka.w;
      acc[0][1] += q0v.x * kb.x + q0v.y * kb.y + q0v.z * kb.z + q0v.w * kb.w;
      acc[0][2] += q0v.x * kc.x + q0v.y * kc.y + q0v.z * kc.z + q0v.w * kc.w;
      acc[0][3] += q0v.x * kd.x + q0v.y * kd.y + q0v.z * kd.z + q0v.w * kd.w;
      acc[1][0] += q1v.x * ka.x + q1v.y * ka.y + q1v.z * ka.z + q1v.w * ka.w;
      acc[1][1] += q1v.x * kb.x + q1v.y * kb.y + q1v.z * kb.z + q1v.w * kb.w;
      acc[1][2] += q1v.x * kc.x + q1v.y * kc.y + q1v.z * kc.z + q1v.w * kc.w;
      acc[1][3] += q1v.x * kd.x + q1v.y * kd.y + q1v.z * kd.z + q1v.w * kd.w;
    }
#pragma unroll
    for (int i = 0; i < 2; ++i) {
      const int sq = q0 + ty * 2 + i;
      float4 mv = *(const float4*)&mask[(size_t)sq * S_ + k0 + tx * 4];
      float4 o;
      o.x = acc[i][0] * 0.125f + mv.x;
      o.y = acc[i][1] * 0.125f + mv.y;
      o.z = acc[i][2] * 0.125f + mv.z;
      o.w = acc[i][3] * 0.125f + mv.w;
      *(float4*)&attn[((size_t)bh * S_ + sq) * S_ + k0 + tx * 4] = o;
    }
  }
}

// ---------------------------------------------------------------------------
// K3: softmax over raw scores (in-place → attn) + O = P V  → ws (over q)
// ---------------------------------------------------------------------------
__global__ __launch_bounds__(256) void k_softmax_pv(
    const float* __restrict__ vws, float* __restrict__ attn,
    float* __restrict__ ows) {
  __shared__ float Vs[64][68];  // transposed: Vs[d][kk]
  __shared__ float Ps[32][68];
  __shared__ float rowm[32], rowr[32];
  const int t = threadIdx.x;
  const int bh = blockIdx.y;
  const int b = bh >> 4, h = bh & 15;
  const int q0 = blockIdx.x * 32;
  const int lane = t & 63, w = t >> 6;
  // phase A: row max & expsum
  for (int rr = 0; rr < 8; ++rr) {
    const int row = w * 8 + rr;
    const float* rp = &attn[((size_t)bh * S_ + q0 + row) * S_];
    float vals[16];
    float mx = -1e30f;
#pragma unroll
    for (int u = 0; u < 16; ++u) { vals[u] = rp[lane + 64 * u]; mx = fmaxf(mx, vals[u]); }
    for (int off = 32; off; off >>= 1) mx = fmaxf(mx, __shfl_xor(mx, off));
    float sm = 0.f;
#pragma unroll
    for (int u = 0; u < 16; ++u) sm += __expf(vals[u] - mx);
    for (int off = 32; off; off >>= 1) sm += __shfl_xor(sm, off);
    if (lane == 0) { rowm[row] = mx; rowr[row] = 1.0f / sm; }
  }
  __syncthreads();
  const int tx = t & 15, ty = t >> 4;
  float oacc[2][4] = {};
  for (int k0 = 0; k0 < S_; k0 += 64) {
    __syncthreads();
    // V tile transposed into LDS
    for (int idx = t; idx < 64 * 16; idx += 256) {
      const int r = idx >> 4, c = (idx & 15) * 4;
      float4 vv = *(const float4*)&vws[((size_t)bh * S_ + k0 + r) * D_ + c];
      Vs[c + 0][r] = vv.x; Vs[c + 1][r] = vv.y; Vs[c + 2][r] = vv.z; Vs[c + 3][r] = vv.w;
    }
    // P tile: normalize raw → write attn (in-place) + LDS
    for (int idx = t; idx < 32 * 16; idx += 256) {
      const int r = idx >> 4, c = (idx & 15) * 4;
      const size_t ga = ((size_t)bh * S_ + q0 + r) * S_ + k0 + c;
      float4 rv = *(const float4*)&attn[ga];
      const float m = rowm[r], rs = rowr[r];
      float4 p;
      p.x = __expf(rv.x - m) * rs;
      p.y = __expf(rv.y - m) * rs;
      p.z = __expf(rv.z - m) * rs;
      p.w = __expf(rv.w - m) * rs;
      *(float4*)&attn[ga] = p;
      *(float4*)&Ps[r][c] = p;
    }
    __syncthreads();
#pragma unroll
    for (int k4 = 0; k4 < 16; ++k4) {
      float4 p0 = *(const float4*)&Ps[ty * 2 + 0][k4 * 4];
      float4 p1 = *(const float4*)&Ps[ty * 2 + 1][k4 * 4];
      float4 va = *(const float4*)&Vs[tx * 4 + 0][k4 * 4];
      float4 vb = *(const float4*)&Vs[tx * 4 + 1][k4 * 4];
      float4 vc = *(const float4*)&Vs[tx * 4 + 2][k4 * 4];
      float4 vd = *(const float4*)&Vs[tx * 4 + 3][k4 * 4];
      oacc[0][0] += p0.x * va.x + p0.y * va.y + p0.z * va.z + p0.w * va.w;
      oacc[0][1] += p0.x * vb.x + p0.y * vb.y + p0.z * vb.z + p0.w * vb.w;
      oacc[0][2] += p0.x * vc.x + p0.y * vc.y + p0.z * vc.z + p0.w * vc.w;
      oacc[0][3] += p0.x * vd.x + p0.y * vd.y + p0.z * vd.z + p0.w * vd.w;
      oacc[1][0] += p1.x * va.x + p1.y * va.y + p1.z * va.z + p1.w * va.w;
      oacc[1][1] += p1.x * vb.x + p1.y * vb.y + p1.z * vb.z + p1.w * vb.w;
      oacc[1][2] += p1.x * vc.x + p1.y * vc.y + p1.z * vc.z + p1.w * vc.w;
      oacc[1][3] += p1.x * vd.x + p1.y * vd.y + p1.z * vd.z + p1.w * vd.w;
    }
  }
#pragma unroll
  for (int i = 0; i < 2; ++i) {
    const int sq = q0 + ty * 2 + i;
    float4 o = make_float4(oacc[i][0], oacc[i][1], oacc[i][2], oacc[i][3]);
    *(float4*)&ows[((size_t)(b * S_ + sq)) * E_ + h * D_ + tx * 4] = o;
  }
}

// ---------------------------------------------------------------------------
// K4: final = O @ Wout^T + b_out   (M=4096, N=1024, K=1024)
// ---------------------------------------------------------------------------
__global__ __launch_bounds__(256) void k_outproj(
    const float* __restrict__ O, const float* __restrict__ W,
    const float* __restrict__ bout, float* __restrict__ out) {
  __shared__ float As[16][68];
  __shared__ float Bs[16][68];
  const int t = threadIdx.x;
  const int tx = t & 15, ty = t >> 4;
  const int m0 = blockIdx.y * 64, n0 = blockIdx.x * 64;
  const int lr = t >> 2;
  const int lc = (t & 3) * 4;
  float acc[4][4] = {};
  for (int k0 = 0; k0 < 1024; k0 += 16) {
    float4 av = *(const float4*)&O[(size_t)(m0 + lr) * 1024 + k0 + lc];
    float4 bv = *(const float4*)&W[(size_t)(n0 + lr) * 1024 + k0 + lc];
    __syncthreads();
    As[lc + 0][lr] = av.x; As[lc + 1][lr] = av.y; As[lc + 2][lr] = av.z; As[lc + 3][lr] = av.w;
    Bs[lc + 0][lr] = bv.x; Bs[lc + 1][lr] = bv.y; Bs[lc + 2][lr] = bv.z; Bs[lc + 3][lr] = bv.w;
    __syncthreads();
#pragma unroll
    for (int kk = 0; kk < 16; ++kk) {
      float4 a = *(const float4*)&As[kk][ty * 4];
      float4 b = *(const float4*)&Bs[kk][tx * 4];
      acc[0][0] += a.x * b.x; acc[0][1] += a.x * b.y; acc[0][2] += a.x * b.z; acc[0][3] += a.x * b.w;
      acc[1][0] += a.y * b.x; acc[1][1] += a.y * b.y; acc[1][2] += a.y * b.z; acc[1][3] += a.y * b.w;
      acc[2][0] += a.z * b.x; acc[2][1] += a.z * b.y; acc[2][2] += a.z * b.z; acc[2][3] += a.z * b.w;
      acc[3][0] += a.w * b.x; acc[3][1] += a.w * b.y; acc[3][2] += a.w * b.z; acc[3][3] += a.w * b.w;
    }
  }
  const int nb = n0 + tx * 4;
  float4 bb = *(const float4*)&bout[nb];
#pragma unroll
  for (int i = 0; i < 4; ++i) {
    const int m = m0 + ty * 4 + i;
    float4 o = make_float4(acc[i][0] + bb.x, acc[i][1] + bb.y,
                           acc[i][2] + bb.z, acc[i][3] + bb.w);
    *(float4*)&out[(size_t)m * 1024 + nb] = o;
  }
}

// ---------------------------------------------------------------------------
extern "C" void kernel_launch(void* const* d_in, const int* in_sizes, int n_in,
                              void* d_out, int out_size, void* d_ws, size_t ws_size,
                              hipStream_t stream) {
  const float* x    = (const float*)d_in[0];
  const float* mask = (const float*)d_in[1];
  const float* cosb = (const float*)d_in[2];
  const float* sinb = (const float*)d_in[3];
  const float* wqkv = (const float*)d_in[4];
  const float* wout = (const float*)d_in[5];
  const float* bout = (const float*)d_in[6];

  float* out  = (float*)d_out;                 // final: 4194304 floats
  float* attn = out + (size_t)4194304;         // attn:  67108864 floats

  float* ws  = (float*)d_ws;
  float* qws = ws;                 // BHSD floats
  float* kws = ws + BHSD;
  float* vws = ws + 2 * BHSD;
  float* ows = ws;                 // O overwrites q (dead after K2)

  k_qkv_rope<<<dim3(48, 64), 256, 0, stream>>>(x, wqkv, cosb, sinb, ws);
  k_scores<<<dim3(32, 64), 256, 0, stream>>>(qws, kws, mask, attn);
  k_softmax_pv<<<dim3(32, 64), 256, 0, stream>>>(vws, attn, ows);
  k_outproj<<<dim3(16, 64), 256, 0, stream>>>(ows, wout, bout, out);
}

// Round 2
// 615.284 us; speedup vs baseline: 2.3558x; 2.3558x over previous
//
#include <hip/hip_runtime.h>
#include <hip/hip_bf16.h>
#include <math.h>

#define S_ 1024
#define E_ 1024
#define H_ 16
#define D_ 64

typedef __attribute__((ext_vector_type(8))) short sv8;   // 8 bf16 (4 VGPR) MFMA A/B frag
typedef __attribute__((ext_vector_type(4))) short sv4;   // 4 bf16
typedef __attribute__((ext_vector_type(4))) float f4;    // MFMA C/D frag

__device__ __forceinline__ short f2b(float f) {
  union { __hip_bfloat16 h; short s; } u;
  u.h = __float2bfloat16(f);
  return u.s;
}

// ---------------------------------------------------------------------------
// K0: fp32 -> bf16 convert of x (4M), w_qkv (3M), w_out (1M) into contiguous dst
// ---------------------------------------------------------------------------
__global__ void k_cvt(const float* __restrict__ x, const float* __restrict__ wqkv,
                      const float* __restrict__ wout, short* __restrict__ dst) {
  const long total = 8388608 / 4;  // 2M float4
  for (long i = (long)blockIdx.x * blockDim.x + threadIdx.x; i < total;
       i += (long)gridDim.x * blockDim.x) {
    const long e = i * 4;
    float4 v;
    if (e < 4194304L)       v = *(const float4*)&x[e];
    else if (e < 7340032L)  v = *(const float4*)&wqkv[e - 4194304L];
    else                    v = *(const float4*)&wout[e - 7340032L];
    sv4 o;
    o[0] = f2b(v.x); o[1] = f2b(v.y); o[2] = f2b(v.z); o[3] = f2b(v.w);
    *(sv4*)&dst[e] = o;
  }
}

// ---------------------------------------------------------------------------
// K1: qkv = Xb @ Wb^T  (M=4096, N=3072, K=1024) bf16 MFMA, direct-frag loads.
// Epilogue: RoPE on q,k; scatter q,k -> (bh,s,d) bf16; v -> vT (bh,d,s) bf16.
// A-frag (16x32): row=lane&15, k=(lane>>4)*8+j.  B-frag: col=lane&15, same k.
// C-frag: col=lane&15, row=(lane>>4)*4+g.
// ---------------------------------------------------------------------------
__global__ __launch_bounds__(256) void k_qkv_rope(
    const short* __restrict__ Xb, const short* __restrict__ Wb,
    const float* __restrict__ cosb, const float* __restrict__ sinb,
    short* __restrict__ qk, short* __restrict__ vT) {
  const int t = threadIdx.x;
  const int w = t >> 6, lane = t & 63, lr = lane & 15, lh = lane >> 4;
  const int m_w = blockIdx.y * 128 + (w & 1) * 64;
  const int n_w = blockIdx.x * 128 + (w >> 1) * 64;
  f4 acc[4][4] = {};
  for (int k0 = 0; k0 < 1024; k0 += 32) {
    sv8 a[4], b[4];
#pragma unroll
    for (int mt = 0; mt < 4; ++mt)
      a[mt] = *(const sv8*)&Xb[(size_t)(m_w + mt * 16 + lr) * 1024 + k0 + lh * 8];
#pragma unroll
    for (int nt = 0; nt < 4; ++nt)
      b[nt] = *(const sv8*)&Wb[(size_t)(n_w + nt * 16 + lr) * 1024 + k0 + lh * 8];
#pragma unroll
    for (int mt = 0; mt < 4; ++mt)
#pragma unroll
      for (int nt = 0; nt < 4; ++nt)
        acc[mt][nt] = __builtin_amdgcn_mfma_f32_16x16x32_bf16(a[mt], b[nt], acc[mt][nt], 0, 0, 0);
  }
#pragma unroll
  for (int nt = 0; nt < 4; ++nt) {
    const int n = n_w + nt * 16 + lr;
    const int which = n >> 10;           // 0=q 1=k 2=v (uniform across wave)
    const int e = n & 1023, h = e >> 6, d = e & 63;
#pragma unroll
    for (int mt = 0; mt < 4; ++mt) {
#pragma unroll
      for (int g = 0; g < 4; ++g) {
        const int m = m_w + mt * 16 + lh * 4 + g;
        const int bb = m >> 10, s = m & 1023;
        float v = acc[mt][nt][g];
        if (which < 2) {
          const float part = __shfl_xor(v, 1);
          const float c = cosb[s * 64 + (d & ~1)];
          const float sn = sinb[s * 64 + (d & ~1)];
          v = (d & 1) ? (part * sn + v * c) : (v * c - part * sn);
          qk[(size_t)which * 4194304 + ((size_t)((bb * 16 + h) * 1024 + s)) * 64 + d] = f2b(v);
        } else {
          vT[((size_t)((bb * 16 + h) * 64 + d)) * 1024 + s] = f2b(v);
        }
      }
    }
  }
}

// ---------------------------------------------------------------------------
// K2: fused scores -> softmax -> attn write -> PV.
// Block: one (bh, 32-q-row tile). 4 waves x 256 keys each.
// Full 32x1024 score row-block lives in registers (acc[2][16] f4 per lane).
// ---------------------------------------------------------------------------
__global__ __launch_bounds__(256) void k_attn(
    const short* __restrict__ qk, const short* __restrict__ vT,
    const float* __restrict__ mask, float* __restrict__ attn,
    short* __restrict__ ows) {
  __shared__ float Pl[4][32][68];     // per-wave P subtile / O partials (reused)
  __shared__ float redm[4][32], reds[4][32];
  const int t = threadIdx.x;
  const int w = t >> 6, lane = t & 63, lr = lane & 15, lh = lane >> 4;
  const int bh = blockIdx.y, q0 = blockIdx.x * 32;
  const int b = bh >> 4, h = bh & 15;
  const short* q = qk;
  const short* kk = qk + 4194304;

  // Q fragments (rows q0..q0+31, d 0..63)
  sv8 qa[2][2];
#pragma unroll
  for (int mt = 0; mt < 2; ++mt)
#pragma unroll
    for (int kt = 0; kt < 2; ++kt)
      qa[mt][kt] = *(const sv8*)&q[((size_t)bh * 1024 + q0 + mt * 16 + lr) * 64 + kt * 32 + lh * 8];

  // QK^T: wave w covers keys [w*256, w*256+256)
  f4 acc[2][16] = {};
#pragma unroll
  for (int ct = 0; ct < 16; ++ct) {
    sv8 kb[2];
#pragma unroll
    for (int kt = 0; kt < 2; ++kt)
      kb[kt] = *(const sv8*)&kk[((size_t)bh * 1024 + w * 256 + ct * 16 + lr) * 64 + kt * 32 + lh * 8];
#pragma unroll
    for (int mt = 0; mt < 2; ++mt)
#pragma unroll
      for (int kt = 0; kt < 2; ++kt)
        acc[mt][ct] = __builtin_amdgcn_mfma_f32_16x16x32_bf16(qa[mt][kt], kb[kt], acc[mt][ct], 0, 0, 0);
  }

  // scale + mask
#pragma unroll
  for (int mt = 0; mt < 2; ++mt)
#pragma unroll
    for (int ct = 0; ct < 16; ++ct)
#pragma unroll
      for (int g = 0; g < 4; ++g)
        acc[mt][ct][g] = acc[mt][ct][g] * 0.125f +
            mask[(size_t)(q0 + mt * 16 + lh * 4 + g) * 1024 + w * 256 + ct * 16 + lr];

  // per-wave row max -> LDS
#pragma unroll
  for (int mt = 0; mt < 2; ++mt)
#pragma unroll
    for (int g = 0; g < 4; ++g) {
      float m = -1e30f;
#pragma unroll
      for (int ct = 0; ct < 16; ++ct) m = fmaxf(m, acc[mt][ct][g]);
      m = fmaxf(m, __shfl_xor(m, 1));
      m = fmaxf(m, __shfl_xor(m, 2));
      m = fmaxf(m, __shfl_xor(m, 4));
      m = fmaxf(m, __shfl_xor(m, 8));
      if (lr == 0) redm[w][mt * 16 + lh * 4 + g] = m;
    }
  __syncthreads();

  // global row max, exp in place, per-wave expsum -> LDS
#pragma unroll
  for (int mt = 0; mt < 2; ++mt)
#pragma unroll
    for (int g = 0; g < 4; ++g) {
      const int row = mt * 16 + lh * 4 + g;
      const float m = fmaxf(fmaxf(redm[0][row], redm[1][row]),
                            fmaxf(redm[2][row], redm[3][row]));
      float s = 0.f;
#pragma unroll
      for (int ct = 0; ct < 16; ++ct) {
        const float e = __expf(acc[mt][ct][g] - m);
        acc[mt][ct][g] = e;
        s += e;
      }
      s += __shfl_xor(s, 1);
      s += __shfl_xor(s, 2);
      s += __shfl_xor(s, 4);
      s += __shfl_xor(s, 8);
      if (lr == 0) reds[w][row] = s;
    }
  __syncthreads();

  // normalize, write attn (fp32, the mandatory 256MB), keep p in acc
#pragma unroll
  for (int mt = 0; mt < 2; ++mt)
#pragma unroll
    for (int g = 0; g < 4; ++g) {
      const int row = mt * 16 + lh * 4 + g;
      const float r = 1.f / (reds[0][row] + reds[1][row] + reds[2][row] + reds[3][row]);
#pragma unroll
      for (int ct = 0; ct < 16; ++ct) {
        const float p = acc[mt][ct][g] * r;
        acc[mt][ct][g] = p;
        attn[((size_t)bh * 1024 + q0 + row) * 1024 + w * 256 + ct * 16 + lr] = p;
      }
    }

  // PV: per 64-key subchunk, P through per-wave LDS tile (C-layout -> A-layout)
  f4 of[2][4] = {};
  for (int sc = 0; sc < 4; ++sc) {
    asm volatile("s_waitcnt lgkmcnt(0)" ::: "memory");  // WAR guard on Pl reuse
#pragma unroll
    for (int mt = 0; mt < 2; ++mt)
#pragma unroll
      for (int ci = 0; ci < 4; ++ci)
#pragma unroll
        for (int g = 0; g < 4; ++g)
          Pl[w][mt * 16 + lh * 4 + g][ci * 16 + lr] = acc[mt][sc * 4 + ci][g];
#pragma unroll
    for (int ktl = 0; ktl < 2; ++ktl) {
      sv8 pa[2];
#pragma unroll
      for (int mt = 0; mt < 2; ++mt) {
        const float* pp = &Pl[w][mt * 16 + lr][ktl * 32 + lh * 8];
        const float4 x0 = *(const float4*)pp;
        const float4 x1 = *(const float4*)(pp + 4);
        sv8 r;
        r[0] = f2b(x0.x); r[1] = f2b(x0.y); r[2] = f2b(x0.z); r[3] = f2b(x0.w);
        r[4] = f2b(x1.x); r[5] = f2b(x1.y); r[6] = f2b(x1.z); r[7] = f2b(x1.w);
        pa[mt] = r;
      }
#pragma unroll
      for (int nt = 0; nt < 4; ++nt) {
        const sv8 vb = *(const sv8*)&vT[((size_t)bh * 64 + nt * 16 + lr) * 1024 +
                                        w * 256 + sc * 64 + ktl * 32 + lh * 8];
#pragma unroll
        for (int mt = 0; mt < 2; ++mt)
          of[mt][nt] = __builtin_amdgcn_mfma_f32_16x16x32_bf16(pa[mt], vb, of[mt][nt], 0, 0, 0);
      }
    }
  }

  // cross-wave O reduction via Pl (each wave owns its own slice; then combine)
  asm volatile("s_waitcnt lgkmcnt(0)" ::: "memory");
#pragma unroll
  for (int mt = 0; mt < 2; ++mt)
#pragma unroll
    for (int nt = 0; nt < 4; ++nt)
#pragma unroll
      for (int g = 0; g < 4; ++g)
        Pl[w][mt * 16 + lh * 4 + g][nt * 16 + lr] = of[mt][nt][g];
  __syncthreads();
  {
    const int row = t >> 3, c8 = (t & 7) * 8;
    sv8 oa;
#pragma unroll
    for (int j = 0; j < 8; ++j) {
      const float v = Pl[0][row][c8 + j] + Pl[1][row][c8 + j] +
                      Pl[2][row][c8 + j] + Pl[3][row][c8 + j];
      oa[j] = f2b(v);
    }
    *(sv8*)&ows[((size_t)(b * 1024) + q0 + row) * 1024 + h * 64 + c8] = oa;
  }
}

// ---------------------------------------------------------------------------
// K4: out = O @ Wout^T + b  (M=4096, N=1024, K=1024) bf16 MFMA direct-frag
// ---------------------------------------------------------------------------
__global__ __launch_bounds__(256) void k_outproj(
    const short* __restrict__ Ob, const short* __restrict__ Wb,
    const float* __restrict__ bout, float* __restrict__ out) {
  const int t = threadIdx.x;
  const int w = t >> 6, lane = t & 63, lr = lane & 15, lh = lane >> 4;
  const int m_w = blockIdx.y * 128 + (w & 1) * 64;
  const int n_w = blockIdx.x * 128 + (w >> 1) * 64;
  f4 acc[4][4] = {};
  for (int k0 = 0; k0 < 1024; k0 += 32) {
    sv8 a[4], b[4];
#pragma unroll
    for (int mt = 0; mt < 4; ++mt)
      a[mt] = *(const sv8*)&Ob[(size_t)(m_w + mt * 16 + lr) * 1024 + k0 + lh * 8];
#pragma unroll
    for (int nt = 0; nt < 4; ++nt)
      b[nt] = *(const sv8*)&Wb[(size_t)(n_w + nt * 16 + lr) * 1024 + k0 + lh * 8];
#pragma unroll
    for (int mt = 0; mt < 4; ++mt)
#pragma unroll
      for (int nt = 0; nt < 4; ++nt)
        acc[mt][nt] = __builtin_amdgcn_mfma_f32_16x16x32_bf16(a[mt], b[nt], acc[mt][nt], 0, 0, 0);
  }
#pragma unroll
  for (int nt = 0; nt < 4; ++nt) {
    const int n = n_w + nt * 16 + lr;
    const float bb = bout[n];
#pragma unroll
    for (int mt = 0; mt < 4; ++mt)
#pragma unroll
      for (int g = 0; g < 4; ++g) {
        const int m = m_w + mt * 16 + lh * 4 + g;
        out[(size_t)m * 1024 + n] = acc[mt][nt][g] + bb;
      }
  }
}

// ---------------------------------------------------------------------------
extern "C" void kernel_launch(void* const* d_in, const int* in_sizes, int n_in,
                              void* d_out, int out_size, void* d_ws, size_t ws_size,
                              hipStream_t stream) {
  const float* x    = (const float*)d_in[0];
  const float* mask = (const float*)d_in[1];
  const float* cosb = (const float*)d_in[2];
  const float* sinb = (const float*)d_in[3];
  const float* wqkv = (const float*)d_in[4];
  const float* wout = (const float*)d_in[5];
  const float* bout = (const float*)d_in[6];

  float* out  = (float*)d_out;
  float* attn = out + (size_t)4194304;

  // ws layout (shorts): [xb 4M][wqkvb 3M][woutb 1M][q 4M][k 4M][vT 4M][ows 4M] = 48MB
  short* wsb   = (short*)d_ws;
  short* xb    = wsb;                       // + wqkvb at 4M, woutb at 7M
  short* wqkvb = wsb + 4194304L;
  short* woutb = wsb + 7340032L;
  short* qk    = wsb + 8388608L;            // q then k
  short* vT    = wsb + 16777216L;
  short* ows   = wsb + 20971520L;

  k_cvt<<<2048, 256, 0, stream>>>(x, wqkv, wout, xb);
  k_qkv_rope<<<dim3(24, 32), 256, 0, stream>>>(xb, wqkvb, cosb, sinb, qk, vT);
  k_attn<<<dim3(32, 64), 256, 0, stream>>>(qk, vT, mask, attn, ows);
  k_outproj<<<dim3(8, 32), 256, 0, stream>>>(ows, woutb, bout, out);
}

// Round 5
// 532.512 us; speedup vs baseline: 2.7220x; 1.1554x over previous
//
#include <hip/hip_runtime.h>
#include <hip/hip_bf16.h>
#include <math.h>

typedef __attribute__((ext_vector_type(8))) short sv8;   // 8 bf16 MFMA A/B frag
typedef __attribute__((ext_vector_type(4))) short sv4;
typedef __attribute__((ext_vector_type(4))) float f4;    // MFMA C/D frag

typedef __attribute__((address_space(3))) void lds_void_t;
typedef __attribute__((address_space(1))) void g_void_t;
#define GLD16(gp, lp) __builtin_amdgcn_global_load_lds((g_void_t*)(gp), (lds_void_t*)(lp), 16, 0, 0)

__device__ __forceinline__ short f2b(float f) {
  union { __hip_bfloat16 h; short s; } u;
  u.h = __float2bfloat16(f);
  return u.s;
}
__device__ __forceinline__ unsigned pk2(float a, float b) {
  return ((unsigned)(unsigned short)f2b(b) << 16) | (unsigned)(unsigned short)f2b(a);
}

// ---------------------------------------------------------------------------
// K0: fp32 -> bf16 convert of x (4M), w_qkv (3M), w_out (1M)
// ---------------------------------------------------------------------------
__global__ void k_cvt(const float* __restrict__ x, const float* __restrict__ wqkv,
                      const float* __restrict__ wout, short* __restrict__ dst) {
  const long total = 8388608 / 4;
  for (long i = (long)blockIdx.x * blockDim.x + threadIdx.x; i < total;
       i += (long)gridDim.x * blockDim.x) {
    const long e = i * 4;
    float4 v;
    if (e < 4194304L)       v = *(const float4*)&x[e];
    else if (e < 7340032L)  v = *(const float4*)&wqkv[e - 4194304L];
    else                    v = *(const float4*)&wout[e - 7340032L];
    sv4 o;
    o[0] = f2b(v.x); o[1] = f2b(v.y); o[2] = f2b(v.z); o[3] = f2b(v.w);
    *(sv4*)&dst[e] = o;
  }
}

// ---------------------------------------------------------------------------
// K1: qkv = Xb @ Wb^T (M=4096,N=3072,K=1024), m97-style LDS staging.
// 128x128 block, 4 waves (64x64 each), BK=32. RoPE epilogue + scatter.
// ---------------------------------------------------------------------------
__global__ __launch_bounds__(256) void k_qkv_rope(
    const short* __restrict__ Xb, const short* __restrict__ Wb,
    const float* __restrict__ cosb, const float* __restrict__ sinb,
    short* __restrict__ qk, short* __restrict__ vT) {
  __shared__ short As[4096], Bs[4096];   // [128 rows][32 k] bf16, 8KB each
  const int t = threadIdx.x;
  const int w = t >> 6, lane = t & 63, lr = lane & 15, lh = lane >> 4;
  const int m0 = blockIdx.y * 128, n0 = blockIdx.x * 128;
  const int mw = (w >> 1) * 64, nw = (w & 1) * 64;
  f4 acc[4][4] = {};
  const int o0 = w * 1024 + lane * 16;        // byte offset in 8KB tile, issue 0
  const int r0 = o0 >> 6, cb0 = o0 & 63;
  const int o1 = o0 + 4096;
  const int r1 = o1 >> 6, cb1 = o1 & 63;
  for (int k0 = 0; k0 < 1024; k0 += 32) {
    __syncthreads();  // WAR on LDS
    GLD16((const char*)Xb + ((size_t)(m0 + r0) * 1024 + k0) * 2 + cb0, (char*)As + w * 1024);
    GLD16((const char*)Wb + ((size_t)(n0 + r0) * 1024 + k0) * 2 + cb0, (char*)Bs + w * 1024);
    GLD16((const char*)Xb + ((size_t)(m0 + r1) * 1024 + k0) * 2 + cb1, (char*)As + w * 1024 + 4096);
    GLD16((const char*)Wb + ((size_t)(n0 + r1) * 1024 + k0) * 2 + cb1, (char*)Bs + w * 1024 + 4096);
    __syncthreads();  // drains vmcnt before barrier (compiler-inserted)
    sv8 a[4], b[4];
#pragma unroll
    for (int mt = 0; mt < 4; ++mt) a[mt] = *(const sv8*)&As[(mw + mt * 16 + lr) * 32 + lh * 8];
#pragma unroll
    for (int nt = 0; nt < 4; ++nt) b[nt] = *(const sv8*)&Bs[(nw + nt * 16 + lr) * 32 + lh * 8];
#pragma unroll
    for (int mt = 0; mt < 4; ++mt)
#pragma unroll
      for (int nt = 0; nt < 4; ++nt)
        acc[mt][nt] = __builtin_amdgcn_mfma_f32_16x16x32_bf16(a[mt], b[nt], acc[mt][nt], 0, 0, 0);
  }
#pragma unroll
  for (int nt = 0; nt < 4; ++nt) {
    const int n = n0 + nw + nt * 16 + lr;
    const int which = n >> 10;          // 0=q 1=k 2=v
    const int e = n & 1023, h = e >> 6, d = e & 63;
#pragma unroll
    for (int mt = 0; mt < 4; ++mt)
#pragma unroll
      for (int g = 0; g < 4; ++g) {
        const int m = m0 + mw + mt * 16 + lh * 4 + g;
        const int bb = m >> 10, s = m & 1023;
        float v = acc[mt][nt][g];
        if (which < 2) {
          const float part = __shfl_xor(v, 1);
          const float c = cosb[s * 64 + (d & ~1)];
          const float sn = sinb[s * 64 + (d & ~1)];
          v = (d & 1) ? (part * sn + v * c) : (v * c - part * sn);
          qk[(size_t)which * 4194304 + ((size_t)((bb * 16 + h) * 1024 + s)) * 64 + d] = f2b(v);
        } else {
          vT[((size_t)((bb * 16 + h) * 64 + d)) * 1024 + s] = f2b(v);
        }
      }
  }
}

// ---------------------------------------------------------------------------
// K2: fused scores->softmax->attn->PV, SWAPPED QK^T (C: col=query, row=key).
// Block = (bh, 32 q-rows); 4 waves x 256 keys. P staged bf16 in swizzled LDS.
// ---------------------------------------------------------------------------
__global__ __launch_bounds__(256) void k_attn(
    const short* __restrict__ qk, const short* __restrict__ vT,
    const float* __restrict__ mask, float* __restrict__ attn,
    short* __restrict__ ows) {
  __shared__ short Pbs[4 * 32 * 256];     // 64KB swizzled P (bf16); later Ol (f32)
  __shared__ float redm[4][32], reds[4][32];
  const int t = threadIdx.x;
  const int w = t >> 6, lane = t & 63, lr = lane & 15, lh = lane >> 4;
  const int bh = blockIdx.y, q0 = blockIdx.x * 32;
  const int b = bh >> 4, h = bh & 15;
  const short* q = qk;
  const short* kk = qk + 4194304;

  // Q fragments (B-operand): col=query
  sv8 qa[2][2];
#pragma unroll
  for (int qt = 0; qt < 2; ++qt)
#pragma unroll
    for (int kt = 0; kt < 2; ++kt)
      qa[qt][kt] = *(const sv8*)&q[((size_t)bh * 1024 + q0 + qt * 16 + lr) * 64 + kt * 32 + lh * 8];

  // QK^T swapped: acc[qt][ct][g] = S[key = w*256+ct*16+lh*4+g][query = q0+qt*16+lr]
  f4 acc[2][16] = {};
#pragma unroll
  for (int ct = 0; ct < 16; ++ct) {
    sv8 kb[2];
#pragma unroll
    for (int kt = 0; kt < 2; ++kt)
      kb[kt] = *(const sv8*)&kk[((size_t)bh * 1024 + w * 256 + ct * 16 + lr) * 64 + kt * 32 + lh * 8];
#pragma unroll
    for (int qt = 0; qt < 2; ++qt)
#pragma unroll
      for (int kt = 0; kt < 2; ++kt)
        acc[qt][ct] = __builtin_amdgcn_mfma_f32_16x16x32_bf16(kb[kt], qa[qt][kt], acc[qt][ct], 0, 0, 0);
  }

  // scale + mask (float4 per (qt,ct))
#pragma unroll
  for (int qt = 0; qt < 2; ++qt)
#pragma unroll
    for (int ct = 0; ct < 16; ++ct) {
      const float4 mv = *(const float4*)&mask[(size_t)(q0 + qt * 16 + lr) * 1024 + w * 256 + ct * 16 + lh * 4];
      acc[qt][ct][0] = acc[qt][ct][0] * 0.125f + mv.x;
      acc[qt][ct][1] = acc[qt][ct][1] * 0.125f + mv.y;
      acc[qt][ct][2] = acc[qt][ct][2] * 0.125f + mv.z;
      acc[qt][ct][3] = acc[qt][ct][3] * 0.125f + mv.w;
    }

  // per-wave row max (row = query)
#pragma unroll
  for (int qt = 0; qt < 2; ++qt) {
    float m = -1e30f;
#pragma unroll
    for (int ct = 0; ct < 16; ++ct)
#pragma unroll
      for (int g = 0; g < 4; ++g) m = fmaxf(m, acc[qt][ct][g]);
    m = fmaxf(m, __shfl_xor(m, 16));
    m = fmaxf(m, __shfl_xor(m, 32));
    if (lane < 16) redm[w][qt * 16 + lr] = m;
  }
  __syncthreads();

  // global max, exp in place, wave expsum
#pragma unroll
  for (int qt = 0; qt < 2; ++qt) {
    const int row = qt * 16 + lr;
    const float gm = fmaxf(fmaxf(redm[0][row], redm[1][row]),
                           fmaxf(redm[2][row], redm[3][row]));
    float s = 0.f;
#pragma unroll
    for (int ct = 0; ct < 16; ++ct)
#pragma unroll
      for (int g = 0; g < 4; ++g) {
        const float e = __expf(acc[qt][ct][g] - gm);
        acc[qt][ct][g] = e;
        s += e;
      }
    s += __shfl_xor(s, 16);
    s += __shfl_xor(s, 32);
    if (lane < 16) reds[w][row] = s;
  }
  __syncthreads();

  // normalize, attn float4 store, P bf16 -> swizzled LDS (b64 writes)
#pragma unroll
  for (int qt = 0; qt < 2; ++qt) {
    const int row = qt * 16 + lr;
    const float r = 1.f / (reds[0][row] + reds[1][row] + reds[2][row] + reds[3][row]);
#pragma unroll
    for (int ct = 0; ct < 16; ++ct) {
      const float p0 = acc[qt][ct][0] * r, p1 = acc[qt][ct][1] * r;
      const float p2 = acc[qt][ct][2] * r, p3 = acc[qt][ct][3] * r;
      float4 st; st.x = p0; st.y = p1; st.z = p2; st.w = p3;
      *(float4*)&attn[((size_t)bh * 1024 + q0 + row) * 1024 + w * 256 + ct * 16 + lh * 4] = st;
      const int col = ct * 16 + lh * 4;
      uint2 u; u.x = pk2(p0, p1); u.y = pk2(p2, p3);
      *(uint2*)&Pbs[(w * 32 + row) * 256 + (col ^ ((row & 7) << 3))] = u;
    }
  }

  // PV: O[q][d] += P[q][keys] * V; pa from own wave's LDS (swizzled reads)
  f4 of[2][4] = {};
  for (int ks = 0; ks < 8; ++ks) {
    sv8 pa[2];
#pragma unroll
    for (int qt = 0; qt < 2; ++qt) {
      const int row = qt * 16 + lr;
      const int col = ks * 32 + lh * 8;
      pa[qt] = *(const sv8*)&Pbs[(w * 32 + row) * 256 + (col ^ ((row & 7) << 3))];
    }
#pragma unroll
    for (int nt = 0; nt < 4; ++nt) {
      const sv8 vb = *(const sv8*)&vT[((size_t)bh * 64 + nt * 16 + lr) * 1024 + w * 256 + ks * 32 + lh * 8];
#pragma unroll
      for (int qt = 0; qt < 2; ++qt)
        of[qt][nt] = __builtin_amdgcn_mfma_f32_16x16x32_bf16(pa[qt], vb, of[qt][nt], 0, 0, 0);
    }
  }

  // cross-wave O combine: overlay Ol (f32) on Pbs
  __syncthreads();   // all waves done reading Pbs
  float* Ol = (float*)Pbs;
#pragma unroll
  for (int qt = 0; qt < 2; ++qt)
#pragma unroll
    for (int nt = 0; nt < 4; ++nt)
#pragma unroll
      for (int g = 0; g < 4; ++g)
        Ol[(w * 32 + qt * 16 + lh * 4 + g) * 68 + nt * 16 + lr] = of[qt][nt][g];
  __syncthreads();
  {
    const int row = t >> 3, c8 = (t & 7) * 8;
    sv8 oa;
#pragma unroll
    for (int j = 0; j < 8; ++j) {
      const float v = Ol[(0 * 32 + row) * 68 + c8 + j] + Ol[(1 * 32 + row) * 68 + c8 + j] +
                      Ol[(2 * 32 + row) * 68 + c8 + j] + Ol[(3 * 32 + row) * 68 + c8 + j];
      oa[j] = f2b(v);
    }
    *(sv8*)&ows[((size_t)(b * 1024) + q0 + row) * 1024 + h * 64 + c8] = oa;
  }
}

// ---------------------------------------------------------------------------
// K4: out = O @ Wout^T + b (M=4096,N=1024,K=1024), m97-style staging
// ---------------------------------------------------------------------------
__global__ __launch_bounds__(256) void k_outproj(
    const short* __restrict__ Ob, const short* __restrict__ Wb,
    const float* __restrict__ bout, float* __restrict__ out) {
  __shared__ short As[4096], Bs[4096];
  const int t = threadIdx.x;
  const int w = t >> 6, lane = t & 63, lr = lane & 15, lh = lane >> 4;
  const int m0 = blockIdx.y * 128, n0 = blockIdx.x * 128;
  const int mw = (w >> 1) * 64, nw = (w & 1) * 64;
  f4 acc[4][4] = {};
  const int o0 = w * 1024 + lane * 16;
  const int r0 = o0 >> 6, cb0 = o0 & 63;
  const int o1 = o0 + 4096;
  const int r1 = o1 >> 6, cb1 = o1 & 63;
  for (int k0 = 0; k0 < 1024; k0 += 32) {
    __syncthreads();
    GLD16((const char*)Ob + ((size_t)(m0 + r0) * 1024 + k0) * 2 + cb0, (char*)As + w * 1024);
    GLD16((const char*)Wb + ((size_t)(n0 + r0) * 1024 + k0) * 2 + cb0, (char*)Bs + w * 1024);
    GLD16((const char*)Ob + ((size_t)(m0 + r1) * 1024 + k0) * 2 + cb1, (char*)As + w * 1024 + 4096);
    GLD16((const char*)Wb + ((size_t)(n0 + r1) * 1024 + k0) * 2 + cb1, (char*)Bs + w * 1024 + 4096);
    __syncthreads();
    sv8 a[4], b[4];
#pragma unroll
    for (int mt = 0; mt < 4; ++mt) a[mt] = *(const sv8*)&As[(mw + mt * 16 + lr) * 32 + lh * 8];
#pragma unroll
    for (int nt = 0; nt < 4; ++nt) b[nt] = *(const sv8*)&Bs[(nw + nt * 16 + lr) * 32 + lh * 8];
#pragma unroll
    for (int mt = 0; mt < 4; ++mt)
#pragma unroll
      for (int nt = 0; nt < 4; ++nt)
        acc[mt][nt] = __builtin_amdgcn_mfma_f32_16x16x32_bf16(a[mt], b[nt], acc[mt][nt], 0, 0, 0);
  }
#pragma unroll
  for (int nt = 0; nt < 4; ++nt) {
    const int n = n0 + nw + nt * 16 + lr;
    const float bb = bout[n];
#pragma unroll
    for (int mt = 0; mt < 4; ++mt)
#pragma unroll
      for (int g = 0; g < 4; ++g) {
        const int m = m0 + mw + mt * 16 + lh * 4 + g;
        out[(size_t)m * 1024 + n] = acc[mt][nt][g] + bb;
      }
  }
}

// ---------------------------------------------------------------------------
extern "C" void kernel_launch(void* const* d_in, const int* in_sizes, int n_in,
                              void* d_out, int out_size, void* d_ws, size_t ws_size,
                              hipStream_t stream) {
  const float* x    = (const float*)d_in[0];
  const float* mask = (const float*)d_in[1];
  const float* cosb = (const float*)d_in[2];
  const float* sinb = (const float*)d_in[3];
  const float* wqkv = (const float*)d_in[4];
  const float* wout = (const float*)d_in[5];
  const float* bout = (const float*)d_in[6];

  float* out  = (float*)d_out;
  float* attn = out + (size_t)4194304;

  short* wsb   = (short*)d_ws;
  short* xb    = wsb;
  short* wqkvb = wsb + 4194304L;
  short* woutb = wsb + 7340032L;
  short* qk    = wsb + 8388608L;   // q then k, (bh,s,d)
  short* vT    = wsb + 16777216L;  // (bh,d,s)
  short* ows   = wsb + 20971520L;  // (b,s,e) bf16

  k_cvt<<<2048, 256, 0, stream>>>(x, wqkv, wout, xb);
  k_qkv_rope<<<dim3(24, 32), 256, 0, stream>>>(xb, wqkvb, cosb, sinb, qk, vT);
  k_attn<<<dim3(32, 64), 256, 0, stream>>>(qk, vT, mask, attn, ows);
  k_outproj<<<dim3(8, 32), 256, 0, stream>>>(ows, woutb, bout, out);
}